// Round 8
// baseline (870.440 us; speedup 1.0000x reference)
//
#include <hip/hip_runtime.h>

#define DD 128
#define NL 4
#define BN_EPS 1e-5f
#define WSTRIDE 16384   // 128*128 bf16 elements per packed matrix
#define CAP 10240       // per-bucket edge capacity
#define CHUNK 8192      // edges per k_scatter block
#define NST 512         // k_stats3 grid
#define RS 136          // LDS x-tile row stride in shorts (128 + 8, keeps 16B align)

typedef __attribute__((ext_vector_type(8))) short short8;
typedef __attribute__((ext_vector_type(4))) float f32x4;

__device__ inline float bf2f(unsigned short u) {
  unsigned int x = ((unsigned int)u) << 16;
  return __builtin_bit_cast(float, x);
}
__device__ inline unsigned short f2bf(float f) {
  unsigned int u = __builtin_bit_cast(unsigned int, f);
  unsigned int r = (u + 0x7fffu + ((u >> 16) & 1u)) >> 16;
  return (unsigned short)r;
}

// ---------------- bucketed CSR build ----------------

__global__ __launch_bounds__(256) void k_scatter(const int* __restrict__ src,
                                                 const int* __restrict__ dst,
                                                 int* __restrict__ fill,
                                                 int* __restrict__ ebuf, int E) {
  __shared__ int hist[256], blkbase[256], cnt2[256];
  int tid = threadIdx.x;
  hist[tid] = 0;
  cnt2[tid] = 0;
  __syncthreads();
  int base = blockIdx.x * CHUNK;
  int cnt = min(CHUNK, E - base);
  for (int i = tid; i < cnt; i += 256) atomicAdd(&hist[dst[base + i] >> 8], 1);
  __syncthreads();
  int h = hist[tid];
  if (h > 0) blkbase[tid] = atomicAdd(&fill[tid], h);
  __syncthreads();
  for (int i = tid; i < cnt; i += 256) {
    int d = dst[base + i];
    int b = d >> 8;
    int off = blkbase[b] + atomicAdd(&cnt2[b], 1);
    if (off < CAP) ebuf[b * CAP + off] = ((d & 255) << 16) | src[base + i];
  }
}

__global__ __launch_bounds__(256) void k_csr(const int* __restrict__ fill,
                                             const int* __restrict__ ebuf,
                                             unsigned short* __restrict__ perm,
                                             int* __restrict__ row_beg,
                                             int* __restrict__ row_end, int n) {
  __shared__ int ncnt[256], lstart[256], cnt2[256], s[256];
  int tid = threadIdx.x;
  int b = blockIdx.x;
  ncnt[tid] = 0;
  cnt2[tid] = 0;
  __syncthreads();
  int cnt = min(fill[b], CAP);
  int base = b * CAP;
  for (int i = tid; i < cnt; i += 256) atomicAdd(&ncnt[ebuf[base + i] >> 16], 1);
  __syncthreads();
  int v = ncnt[tid];
  s[tid] = v;
  __syncthreads();
  for (int off = 1; off < 256; off <<= 1) {
    int x = (tid >= off) ? s[tid - off] : 0;
    __syncthreads();
    s[tid] += x;
    __syncthreads();
  }
  int st = s[tid] - v;
  lstart[tid] = st;
  int node = b * 256 + tid;
  if (node < n) {
    row_beg[node] = base + st;
    row_end[node] = base + st + v;
  }
  __syncthreads();
  for (int i = tid; i < cnt; i += 256) {
    int e = ebuf[base + i];
    int l = e >> 16;
    int pos = lstart[l] + atomicAdd(&cnt2[l], 1);
    perm[base + pos] = (unsigned short)(e & 0xFFFF);
  }
}

// ---------------- W pre-pack: all 9 matrices in one launch ----------------
// m=0: W_emb; m=1..4: W1[m-1]; m=5..8: W2[m-5]

__global__ void k_packW(const float* __restrict__ We, const float* __restrict__ W1,
                        const float* __restrict__ W2, unsigned short* __restrict__ out) {
  int idx = blockIdx.x * 256 + threadIdx.x;
  int m = idx >> 14;
  if (m >= 9) return;
  const float* W;
  if (m == 0) W = We;
  else if (m < 5) W = W1 + (size_t)(m - 1) * DD * DD;
  else W = W2 + (size_t)(m - 5) * DD * DD;
  int o = idx & (WSTRIDE - 1);
  int frag = o >> 9;
  int l = (o >> 3) & 63;
  int j = o & 7;
  int t = frag >> 2, s = frag & 3;
  int k = s * 32 + ((l >> 4) << 3) + j;
  int n = (t << 4) + (l & 15);
  out[(size_t)m * WSTRIDE + o] = f2bf(W[k * DD + n]);
}

// ---------------- stats partial reduce: Spart[nblk][256] -> S[256] ----------------

__global__ __launch_bounds__(256) void k_reduce(const float* __restrict__ Spart,
                                                float* __restrict__ S, int nblk) {
  __shared__ float red[256];
  int tid = threadIdx.x;
  int jj = tid & 7;
  int r = tid >> 3;  // 0..31
  int j = blockIdx.x * 8 + jj;
  float acc = 0.f;
  for (int i = r; i < nblk; i += 32) acc += Spart[(size_t)i * 256 + j];
  red[tid] = acc;
  __syncthreads();
  if (tid < 8) {
    float t = 0.f;
    for (int i = 0; i < 32; ++i) t += red[i * 8 + tid];
    S[blockIdx.x * 8 + tid] = t;
  }
}

// -------- fused aggregate + GEMM1: x never hits global --------
// Block = one 64-node tile. Wave w aggregates nodes w*16..w*16+15 into LDS rows,
// then runs the MFMA GEMM on its own rows. Epilogue = R6 GEMM1 (yb + Spart).

__global__ __launch_bounds__(256) void k_agg_gemm1(
    const unsigned short* __restrict__ hb, const int* __restrict__ row_beg,
    const int* __restrict__ row_end, const unsigned short* __restrict__ perm,
    const float* __restrict__ epsv, int layer, const unsigned short* __restrict__ W1b,
    const float* __restrict__ b1v, unsigned short* __restrict__ Yb,
    float* __restrict__ Spart, int nrows) {
  __shared__ unsigned short xs[64 * RS];
  __shared__ float red[4][2][DD];
  int tid = threadIdx.x;
  int wave = tid >> 6, lane = tid & 63;
  int quad = lane >> 4, n16 = lane & 15;  // quad doubles as edge-slot, n16 as col-chunk
  float ep = 1.0f + epsv[layer];

  // ---- aggregation into LDS ----
  for (int nl = 0; nl < 16; ++nl) {
    int row = wave * 16 + nl;
    int node = blockIdx.x * 64 + row;
    float acc[8] = {0.f, 0.f, 0.f, 0.f, 0.f, 0.f, 0.f, 0.f};
    if (node < nrows) {
      int beg = row_beg[node], end = row_end[node];
      for (int e = beg + quad; e < end; e += 4) {
        int s = perm[e];
        short8 v = *(const short8*)(hb + (size_t)s * DD + n16 * 8);
#pragma unroll
        for (int j = 0; j < 8; ++j) acc[j] += bf2f((unsigned short)v[j]);
      }
    }
#pragma unroll
    for (int j = 0; j < 8; ++j) {
      acc[j] += __shfl_xor(acc[j], 16);
      acc[j] += __shfl_xor(acc[j], 32);
    }
    if (quad == 0) {
      short8 o = {0, 0, 0, 0, 0, 0, 0, 0};
      if (node < nrows) {
        short8 hv = *(const short8*)(hb + (size_t)node * DD + n16 * 8);
#pragma unroll
        for (int j = 0; j < 8; ++j)
          o[j] = (short)f2bf(fmaf(ep, bf2f((unsigned short)hv[j]), acc[j]));
      }
      *(short8*)(xs + row * RS + n16 * 8) = o;
    }
  }
  __syncthreads();

  // ---- GEMM1 from LDS ----
  int m0 = blockIdx.x * 64 + wave * 16;
  f32x4 acc[8];
#pragma unroll
  for (int t = 0; t < 8; ++t) acc[t] = (f32x4){0.f, 0.f, 0.f, 0.f};
  const short8* W8 = (const short8*)W1b;
#pragma unroll
  for (int s = 0; s < 4; ++s) {
    int kbase = s * 32 + quad * 8;
    short8 a = *(const short8*)(xs + (wave * 16 + n16) * RS + kbase);
#pragma unroll
    for (int t = 0; t < 8; ++t) {
      short8 b = W8[(t * 4 + s) * 64 + lane];
      acc[t] = __builtin_amdgcn_mfma_f32_16x16x32_bf16(a, b, acc[t], 0, 0, 0);
    }
  }
#pragma unroll
  for (int t = 0; t < 8; ++t) {
    int col = t * 16 + n16;
    float bv = b1v[col];
    float s_c = 0.f, q_c = 0.f;
#pragma unroll
    for (int r = 0; r < 4; ++r) {
      int row = m0 + quad * 4 + r;
      if (row < nrows) {
        float v = acc[t][r] + bv;
        Yb[(size_t)row * DD + col] = f2bf(v);
        s_c += v;
        q_c += v * v;
      }
    }
    s_c += __shfl_xor(s_c, 16);
    q_c += __shfl_xor(q_c, 16);
    s_c += __shfl_xor(s_c, 32);
    q_c += __shfl_xor(q_c, 32);
    if (quad == 0) {
      red[wave][0][col] = s_c;
      red[wave][1][col] = q_c;
    }
  }
  __syncthreads();
  if (tid < DD) {
    float s4 = red[0][0][tid] + red[1][0][tid] + red[2][0][tid] + red[3][0][tid];
    float q4 = red[0][1][tid] + red[1][1][tid] + red[2][1][tid] + red[3][1][tid];
    Spart[(size_t)blockIdx.x * 256 + tid] = s4;
    Spart[(size_t)blockIdx.x * 256 + DD + tid] = q4;
  }
}

// ---------------- bf16 MFMA GEMM [nrows,128] x [128,128] + bias ----------------
// PRE: relu(x*sc+sh) on A-load, params derived in-prologue from finalized stats.
// STATS: per-block partials to Spart (non-atomic).

template <bool PRE, bool STATS, bool IN_F32, bool OUT_BF16, bool OUT_F32>
__global__ __launch_bounds__(256) void k_gemm_mfma(
    const void* __restrict__ Xv, const unsigned short* __restrict__ Wb,
    const float* __restrict__ bias, const float* __restrict__ statsPre,
    const float* __restrict__ gPre, const float* __restrict__ bPre,
    unsigned short* __restrict__ Yb, float* __restrict__ Yf,
    float* __restrict__ Spart, int nrows, float inv_n) {
  __shared__ float red[4][2][DD];
  __shared__ float s_sc[DD], s_sh[DD];
  int tid = threadIdx.x;
  int wave = tid >> 6, lane = tid & 63;
  int quad = lane >> 4, n16 = lane & 15;
  int m0 = blockIdx.x * 64 + wave * 16;
  int rowA = m0 + n16;

  if (PRE) {
    if (tid < DD) {
      float mu = statsPre[tid] * inv_n;
      float var = statsPre[DD + tid] * inv_n - mu * mu;
      float sc = gPre[tid] * rsqrtf(var + BN_EPS);
      s_sc[tid] = sc;
      s_sh[tid] = fmaf(-mu, sc, bPre[tid]);
    }
    __syncthreads();
  }

  f32x4 acc[8];
#pragma unroll
  for (int t = 0; t < 8; ++t) acc[t] = (f32x4){0.f, 0.f, 0.f, 0.f};

  const short8* W8 = (const short8*)Wb;
#pragma unroll
  for (int s = 0; s < 4; ++s) {
    int kbase = s * 32 + quad * 8;
    short8 a = {0, 0, 0, 0, 0, 0, 0, 0};
    if (rowA < nrows) {
      if (IN_F32) {
        const float* xp = (const float*)Xv + (size_t)rowA * DD + kbase;
        float4 v0 = ((const float4*)xp)[0];
        float4 v1 = ((const float4*)xp)[1];
        a[0] = (short)f2bf(v0.x); a[1] = (short)f2bf(v0.y);
        a[2] = (short)f2bf(v0.z); a[3] = (short)f2bf(v0.w);
        a[4] = (short)f2bf(v1.x); a[5] = (short)f2bf(v1.y);
        a[6] = (short)f2bf(v1.z); a[7] = (short)f2bf(v1.w);
      } else {
        a = *(const short8*)((const unsigned short*)Xv + (size_t)rowA * DD + kbase);
        if (PRE) {
#pragma unroll
          for (int j = 0; j < 8; ++j) {
            float v = bf2f((unsigned short)a[j]);
            v = fmaxf(fmaf(v, s_sc[kbase + j], s_sh[kbase + j]), 0.f);
            a[j] = (short)f2bf(v);
          }
        }
      }
    }
#pragma unroll
    for (int t = 0; t < 8; ++t) {
      short8 b = W8[(t * 4 + s) * 64 + lane];
      acc[t] = __builtin_amdgcn_mfma_f32_16x16x32_bf16(a, b, acc[t], 0, 0, 0);
    }
  }

#pragma unroll
  for (int t = 0; t < 8; ++t) {
    int col = t * 16 + n16;
    float bv = bias[col];
    float s_c = 0.f, q_c = 0.f;
#pragma unroll
    for (int r = 0; r < 4; ++r) {
      int row = m0 + quad * 4 + r;
      if (row < nrows) {
        float v = acc[t][r] + bv;
        if (OUT_BF16) Yb[(size_t)row * DD + col] = f2bf(v);
        if (OUT_F32) Yf[(size_t)row * DD + col] = v;
        if (STATS) { s_c += v; q_c += v * v; }
      }
    }
    if (STATS) {
      s_c += __shfl_xor(s_c, 16);
      q_c += __shfl_xor(q_c, 16);
      s_c += __shfl_xor(s_c, 32);
      q_c += __shfl_xor(q_c, 32);
      if (quad == 0) {
        red[wave][0][col] = s_c;
        red[wave][1][col] = q_c;
      }
    }
  }
  if (STATS) {
    __syncthreads();
    if (tid < DD) {
      float s4 = red[0][0][tid] + red[1][0][tid] + red[2][0][tid] + red[3][0][tid];
      float q4 = red[0][1][tid] + red[1][1][tid] + red[2][1][tid] + red[3][1][tid];
      Spart[(size_t)blockIdx.x * 256 + tid] = s4;
      Spart[(size_t)blockIdx.x * 256 + DD + tid] = q4;
    }
  }
}

// ------- stats of a = relu(bn2(z)), z bf16; non-atomic per-block partials -------

__global__ __launch_bounds__(256) void k_stats3(const unsigned short* __restrict__ Z,
                                                const float* __restrict__ stats2,
                                                const float* __restrict__ g2,
                                                const float* __restrict__ b2v,
                                                float* __restrict__ Spart, int n8,
                                                float inv_n) {
  __shared__ float wred[4][2][DD];
  __shared__ float s_sc[DD], s_sh[DD];
  int tid = threadIdx.x;
  if (tid < DD) {
    float mu = stats2[tid] * inv_n;
    float var = stats2[DD + tid] * inv_n - mu * mu;
    float sc = g2[tid] * rsqrtf(var + BN_EPS);
    s_sc[tid] = sc;
    s_sh[tid] = fmaf(-mu, sc, b2v[tid]);
  }
  __syncthreads();
  int c8 = tid & 15;
  int wave = tid >> 6, lane = tid & 63;
  float sc[8], sh[8];
#pragma unroll
  for (int j = 0; j < 8; ++j) { sc[j] = s_sc[c8 * 8 + j]; sh[j] = s_sh[c8 * 8 + j]; }
  float s[8] = {0, 0, 0, 0, 0, 0, 0, 0};
  float q[8] = {0, 0, 0, 0, 0, 0, 0, 0};
  for (int idx = blockIdx.x * 256 + tid; idx < n8; idx += gridDim.x * 256) {
    short8 z = ((const short8*)Z)[idx];
#pragma unroll
    for (int j = 0; j < 8; ++j) {
      float a = fmaxf(fmaf(bf2f((unsigned short)z[j]), sc[j], sh[j]), 0.f);
      s[j] += a;
      q[j] += a * a;
    }
  }
#pragma unroll
  for (int j = 0; j < 8; ++j) {
    s[j] += __shfl_xor(s[j], 16);
    q[j] += __shfl_xor(q[j], 16);
    s[j] += __shfl_xor(s[j], 32);
    q[j] += __shfl_xor(q[j], 32);
  }
  if (lane < 16) {
#pragma unroll
    for (int j = 0; j < 8; ++j) {
      wred[wave][0][lane * 8 + j] = s[j];
      wred[wave][1][lane * 8 + j] = q[j];
    }
  }
  __syncthreads();
  if (tid < DD) {
    float s4 = wred[0][0][tid] + wred[1][0][tid] + wred[2][0][tid] + wred[3][0][tid];
    float q4 = wred[0][1][tid] + wred[1][1][tid] + wred[2][1][tid] + wred[3][1][tid];
    Spart[(size_t)blockIdx.x * 256 + tid] = s4;
    Spart[(size_t)blockIdx.x * 256 + DD + tid] = q4;
  }
}

// ------- final: h += relu(bn3(relu(bn2(z)))); both BN params in-prologue -------

__global__ __launch_bounds__(256) void k_final(
    const unsigned short* __restrict__ Z, const float* __restrict__ stats2,
    const float* __restrict__ g2, const float* __restrict__ b2v,
    const float* __restrict__ stats3, const float* __restrict__ g3,
    const float* __restrict__ b3v, float* __restrict__ H,
    unsigned short* __restrict__ hbout, int n8, float inv_n) {
  __shared__ float s2l[DD], h2l[DD], s3l[DD], h3l[DD];
  int tid = threadIdx.x;
  if (tid < DD) {
    float mu = stats2[tid] * inv_n;
    float var = stats2[DD + tid] * inv_n - mu * mu;
    float sc = g2[tid] * rsqrtf(var + BN_EPS);
    s2l[tid] = sc;
    h2l[tid] = fmaf(-mu, sc, b2v[tid]);
    mu = stats3[tid] * inv_n;
    var = stats3[DD + tid] * inv_n - mu * mu;
    sc = g3[tid] * rsqrtf(var + BN_EPS);
    s3l[tid] = sc;
    h3l[tid] = fmaf(-mu, sc, b3v[tid]);
  }
  __syncthreads();
  int c8 = tid & 15;
  float s2[8], h2[8], s3[8], h3[8];
#pragma unroll
  for (int j = 0; j < 8; ++j) {
    s2[j] = s2l[c8 * 8 + j]; h2[j] = h2l[c8 * 8 + j];
    s3[j] = s3l[c8 * 8 + j]; h3[j] = h3l[c8 * 8 + j];
  }
  for (int idx = blockIdx.x * 256 + tid; idx < n8; idx += gridDim.x * 256) {
    short8 z = ((const short8*)Z)[idx];
    float4 hv0 = ((const float4*)H)[idx * 2];
    float4 hv1 = ((const float4*)H)[idx * 2 + 1];
    float hv[8] = {hv0.x, hv0.y, hv0.z, hv0.w, hv1.x, hv1.y, hv1.z, hv1.w};
    float o[8];
    short8 ob;
#pragma unroll
    for (int j = 0; j < 8; ++j) {
      float a = fmaxf(fmaf(bf2f((unsigned short)z[j]), s2[j], h2[j]), 0.f);
      o[j] = hv[j] + fmaxf(fmaf(a, s3[j], h3[j]), 0.f);
      ob[j] = (short)f2bf(o[j]);
    }
    ((float4*)H)[idx * 2] = make_float4(o[0], o[1], o[2], o[3]);
    ((float4*)H)[idx * 2 + 1] = make_float4(o[4], o[5], o[6], o[7]);
    *(short8*)(hbout + (size_t)idx * 8) = ob;
  }
}

// ---------------- launch ----------------

extern "C" void kernel_launch(void* const* d_in, const int* in_sizes, int n_in,
                              void* d_out, int out_size, void* d_ws, size_t ws_size,
                              hipStream_t stream) {
  const float* h_in = (const float*)d_in[0];
  const int* src = (const int*)d_in[1];
  const int* dst = (const int*)d_in[2];
  const float* W_emb = (const float*)d_in[3];
  const float* b_emb = (const float*)d_in[4];
  const float* epsv = (const float*)d_in[5];
  const float* W1 = (const float*)d_in[6];
  const float* b1 = (const float*)d_in[7];
  const float* g1 = (const float*)d_in[8];
  const float* be1 = (const float*)d_in[9];
  const float* W2 = (const float*)d_in[10];
  const float* b2 = (const float*)d_in[11];
  const float* ga = (const float*)d_in[12];
  const float* ba = (const float*)d_in[13];
  const float* gl = (const float*)d_in[14];
  const float* bl = (const float*)d_in[15];

  const int Nn = in_sizes[0] / DD;  // 50000
  const int E = in_sizes[1];        // 1600000
  const int nbuck = (Nn + 255) >> 8;
  const int gb = (Nn + 63) / 64;    // 782

  char* ws = (char*)d_ws;
  size_t off = 0;
  auto alloc = [&](size_t bytes) -> void* {
    off = (off + 255) & ~(size_t)255;
    void* p = ws + off;
    off += bytes;
    return p;
  };
  int* ebuf = (int*)alloc((size_t)nbuck * CAP * 4);
  unsigned short* perm = (unsigned short*)alloc((size_t)nbuck * CAP * 2);
  int* fill = (int*)alloc(256 * 4);
  int* row_beg = (int*)alloc((size_t)Nn * 4);
  int* row_end = (int*)alloc((size_t)Nn * 4);
  unsigned short* Wb = (unsigned short*)alloc((size_t)9 * WSTRIDE * 2);
  float* Spart = (float*)alloc((size_t)gb * 256 * 4);
  float* Sfin = (float*)alloc((size_t)3 * 256 * 4);
  unsigned short* hb = (unsigned short*)alloc((size_t)Nn * DD * 2);
  unsigned short* xb = (unsigned short*)alloc((size_t)Nn * DD * 2);  // z buffer
  unsigned short* yb = (unsigned short*)alloc((size_t)Nn * DD * 2);
  float* h = (float*)d_out;  // fp32 h chain lives in d_out

  hipMemsetAsync(fill, 0, 256 * 4, stream);

  // CSR build (bucketed)
  int nblk1 = (E + CHUNK - 1) / CHUNK;
  k_scatter<<<nblk1, 256, 0, stream>>>(src, dst, fill, ebuf, E);
  k_csr<<<nbuck, 256, 0, stream>>>(fill, ebuf, perm, row_beg, row_end, Nn);

  // W pre-pack (bf16, B-fragment order) — all 9 matrices
  k_packW<<<(9 * WSTRIDE + 255) / 256, 256, 0, stream>>>(W_emb, W1, W2, Wb);

  float inv_n = 1.0f / (float)Nn;
  int n8 = Nn * DD / 8;

  // embed: h = h_in @ W_emb + b_emb (fp32 h into d_out + bf16 mirror hb)
  k_gemm_mfma<false, false, true, true, true><<<gb, 256, 0, stream>>>(
      h_in, Wb, b_emb, nullptr, nullptr, nullptr, hb, h, nullptr, Nn, inv_n);

  float* S1 = Sfin;
  float* S2 = Sfin + 256;
  float* S3 = Sfin + 512;
  for (int i = 0; i < NL; ++i) {
    // fused aggregate + GEMM1: hb -> (gather+eps) -> x (LDS) -> y (yb) + S1 partials
    k_agg_gemm1<<<gb, 256, 0, stream>>>(hb, row_beg, row_end, perm, epsv, i,
                                        Wb + (size_t)WSTRIDE * (1 + i), b1 + i * DD,
                                        yb, Spart, Nn);
    k_reduce<<<32, 256, 0, stream>>>(Spart, S1, gb);
    k_gemm_mfma<true, true, false, true, false><<<gb, 256, 0, stream>>>(
        yb, Wb + (size_t)WSTRIDE * (5 + i), b2 + i * DD, S1, g1 + i * DD, be1 + i * DD,
        xb, nullptr, Spart, Nn, inv_n);
    k_reduce<<<32, 256, 0, stream>>>(Spart, S2, gb);
    k_stats3<<<NST, 256, 0, stream>>>(xb, S2, ga + i * DD, ba + i * DD, Spart, n8,
                                      inv_n);
    k_reduce<<<32, 256, 0, stream>>>(Spart, S3, NST);
    k_final<<<2048, 256, 0, stream>>>(xb, S2, ga + i * DD, ba + i * DD, S3, gl + i * DD,
                                      bl + i * DD, h, hb, n8, inv_n);
  }
}